// Round 13
// baseline (1620.818 us; speedup 1.0000x reference)
//
#include <hip/hip_runtime.h>
#include <hip/hip_bf16.h>

#define NN 10000
#define EE 320000
#define ET 64   // edges per block in edge_kernel

typedef __attribute__((ext_vector_type(8))) short bf8_t;   // 8 bf16 (4 VGPR)
typedef __attribute__((ext_vector_type(4))) short s4_t;
typedef __attribute__((ext_vector_type(4))) float f4_t;

__device__ __forceinline__ float b2f(short b){
  union { unsigned u; float f; } v; v.u = ((unsigned)(unsigned short)b) << 16; return v.f;
}
__device__ __forceinline__ short f2b(float f){
  union { float f; unsigned u; } v; v.f = f;
  unsigned r = (v.u + 0x7fffu + ((v.u >> 16) & 1u)) >> 16;
  return (short)r;
}
// native packed f32->bf16 (RNE), 1 inst for 2 elements
__device__ __forceinline__ unsigned cvt2(float lo, float hi){
  unsigned r; asm("v_cvt_pk_bf16_f32 %0, %1, %2" : "=v"(r) : "v"(lo), "v"(hi)); return r;
}
// unpack u32 (2 bf16) -> 2 f32
__device__ __forceinline__ float2 up2(unsigned u){
  union { unsigned v; float f; } a, b;
  a.v = u << 16; b.v = u & 0xffff0000u;
  float2 r; r.x = a.f; r.y = b.f; return r;
}

// staging loaders: 8 contiguous elements -> bf16x8
__device__ __forceinline__ bf8_t load8(const short* p){ return *(const bf8_t*)p; }
__device__ __forceinline__ bf8_t load8(const float* p){
  float4 a = ((const float4*)p)[0], b = ((const float4*)p)[1];
  union { unsigned u[4]; bf8_t v; } o;
  o.u[0] = cvt2(a.x, a.y); o.u[1] = cvt2(a.z, a.w);
  o.u[2] = cvt2(b.x, b.y); o.u[3] = cvt2(b.z, b.w);
  return o.v;
}

// ================= counting sort of edges by dst =================
__global__ void zero_hist(int* __restrict__ hist){
  int i = blockIdx.x * 256 + threadIdx.x;
  if (i < NN) hist[i] = 0;
}
__global__ void count_k(const int* __restrict__ eidx, int* __restrict__ hist){
  int e = blockIdx.x * 256 + threadIdx.x;
  if (e < EE) atomicAdd(&hist[eidx[EE + e]], 1);
}
__global__ void scan_k(const int* __restrict__ hist, int* __restrict__ cursor){
  __shared__ int partsum[256];
  const int tid = threadIdx.x;
  const int base = tid * 40;
  int local[40]; int s = 0;
  for (int j = 0; j < 40; j++){
    int b = base + j; int v = (b < NN) ? hist[b] : 0;
    local[j] = s; s += v;
  }
  partsum[tid] = s;
  __syncthreads();
  if (tid == 0){
    int acc = 0;
    for (int i = 0; i < 256; i++){ int t = partsum[i]; partsum[i] = acc; acc += t; }
  }
  __syncthreads();
  const int off = partsum[tid];
  for (int j = 0; j < 40; j++){
    int b = base + j;
    if (b < NN) cursor[b] = off + local[j];
  }
}
__global__ void scatter_k(const int* __restrict__ eidx, int* __restrict__ cursor,
                          int* __restrict__ ssrc, int* __restrict__ sdst, int* __restrict__ sperm){
  int e = blockIdx.x * 256 + threadIdx.x;
  if (e >= EE) return;
  int d = eidx[EE + e];
  int p = atomicAdd(&cursor[d], 1);
  ssrc[p] = eidx[e]; sdst[p] = d; sperm[p] = e;
}

// ---------------- weight transpose+convert: fusion weights ----------------
__global__ void prep_fusion(const float* __restrict__ sw, const float* __restrict__ ew,
                            const float* __restrict__ gw,
                            short* __restrict__ structT, short* __restrict__ esmT,
                            short* __restrict__ gateT){
  int idx = blockIdx.x * 256 + threadIdx.x;
  if (idx < 256*64){ int o = idx/64, k = idx - o*64; structT[idx] = f2b(sw[k*256+o]); return; }
  idx -= 256*64;
  if (idx < 256*1280){ int o = idx/1280, k = idx - o*1280; esmT[idx] = f2b(ew[k*256+o]); return; }
  idx -= 256*1280;
  if (idx < 256*512){ int o = idx/512, k = idx - o*512; gateT[idx] = f2b(gw[k*256+o]); return; }
}

// ---------------- per-layer weight prep, all 4 layers in one launch (blockIdx.y = layer) ------
__global__ void prep_layer(const float* __restrict__ ew1_0, const float* __restrict__ ew2_0,
                           const float* __restrict__ cw1_0, const float* __restrict__ nw1_0,
                           short* __restrict__ EW1T_0, short* __restrict__ W2T_0,
                           short* __restrict__ Wc1T_0, short* __restrict__ NW1T_0,
                           short* __restrict__ WeT_0){
  const int li = blockIdx.y;
  const float* ew1 = ew1_0 + (size_t)li*529*256;
  const float* ew2 = ew2_0 + (size_t)li*256*256;
  const float* cw1 = cw1_0 + (size_t)li*256*256;
  const float* nw1 = nw1_0 + (size_t)li*512*256;
  short* EW1T = EW1T_0 + (size_t)li*512*256;
  short* W2T  = W2T_0  + (size_t)li*256*256;
  short* Wc1T = Wc1T_0 + (size_t)li*256*256;
  short* NW1T = NW1T_0 + (size_t)li*256*768;
  short* WeT  = WeT_0  + (size_t)li*256*32;
  int idx = blockIdx.x * 256 + threadIdx.x;
  if (idx < 512*256){
    int o = idx >> 8, k = idx & 255;
    float v = (o < 256) ? ew1[k*256 + o] : ew1[(256 + k)*256 + (o - 256)];
    EW1T[idx] = f2b(v); return;
  } idx -= 512*256;
  if (idx < 65536){ int o = idx >> 8, k = idx & 255; W2T[idx] = f2b(ew2[k*256+o]); return; } idx -= 65536;
  if (idx < 65536){ int o = idx >> 8, k = idx & 255; Wc1T[idx] = f2b(cw1[k*256+o]); return; } idx -= 65536;
  if (idx < 256*768){
    int o = idx/768, k = idx - o*768;
    int kk = (k < 512) ? k : (k - 256);
    NW1T[idx] = f2b(nw1[kk*256 + o]); return;
  } idx -= 256*768;
  if (idx < 256*32){
    int o = idx >> 5, k = idx & 31;
    float v = (k < 16) ? ew1[(513 + k)*256 + o] : ((k < 18) ? ew1[512*256 + o] : 0.f);
    WeT[idx] = f2b(v);
  }
}

// ---------------- generic bf16 MFMA GEMM, MT rows per block ----------------
template<bool RELU, typename AT, int MT>
__global__ __launch_bounds__(256, 2) void gemm_bf16(
    const AT* __restrict__ A, const int K, const int lda, const short* __restrict__ WT,
    const float* __restrict__ bias, const int M,
    float* __restrict__ outF, const int ldf,
    short* __restrict__ outB, const int ldb)
{
  __shared__ __align__(16) short at[MT*40];
  const int tid = threadIdx.x;
  const int w = tid >> 6, l = tid & 63;
  const int g = l >> 4, cl = l & 15;
  const int m0 = blockIdx.x * MT;
  const int cb = blockIdx.y * 256 + w * 64;
  const f4_t fz = {0.f, 0.f, 0.f, 0.f};
  f4_t acc[MT/16][4];
#pragma unroll
  for (int fr = 0; fr < MT/16; fr++)
#pragma unroll
    for (int cf = 0; cf < 4; cf++) acc[fr][cf] = fz;
  const int r = tid >> 2, kq = tid & 3;
  for (int k0 = 0; k0 < K; k0 += 32){
    if (r < MT){
      bf8_t av = {0,0,0,0,0,0,0,0};
      if (m0 + r < M) av = load8(A + (size_t)(m0 + r)*lda + k0 + kq*8);
      *(bf8_t*)(&at[r*40 + kq*8]) = av;
    }
    __syncthreads();
    bf8_t bfr[4], afr[MT/16];
#pragma unroll
    for (int cf = 0; cf < 4; cf++)
      bfr[cf] = *(const bf8_t*)(WT + (size_t)(cb + cf*16 + cl)*K + k0 + 8*g);
#pragma unroll
    for (int fr = 0; fr < MT/16; fr++)
      afr[fr] = *(const bf8_t*)(&at[(fr*16 + cl)*40 + 8*g]);
#pragma unroll
    for (int fr = 0; fr < MT/16; fr++)
#pragma unroll
      for (int cf = 0; cf < 4; cf++)
        acc[fr][cf] = __builtin_amdgcn_mfma_f32_16x16x32_bf16(afr[fr], bfr[cf], acc[fr][cf], 0, 0, 0);
    __syncthreads();
  }
#pragma unroll
  for (int fr = 0; fr < MT/16; fr++){
#pragma unroll
    for (int cf = 0; cf < 4; cf++){
      const int col = cb + cf*16 + cl;
      const float bv = bias ? bias[col] : 0.f;
#pragma unroll
      for (int j = 0; j < 4; j++){
        const int row = m0 + fr*16 + 4*g + j;
        if (row < M){
          float v = acc[fr][cf][j] + bv;
          if (RELU) v = fmaxf(v, 0.f);
          if (outF) outF[(size_t)row*ldf + col] = v;
          if (outB) outB[(size_t)row*ldb + col] = f2b(v);
        }
      }
    }
  }
}

// ---------------- gate GEMM with fused dot-product reduction (32 rows/block) ----------------
__global__ __launch_bounds__(256, 2) void gate_gemm(
    const short* __restrict__ A, const short* __restrict__ WT,
    const float* __restrict__ bias, const float* __restrict__ gw2,
    float* __restrict__ gatez)
{
  __shared__ __align__(16) short at[32*40];
  __shared__ float psum[4][32];
  const int K = 512;
  const int tid = threadIdx.x;
  const int w = tid >> 6, l = tid & 63;
  const int g = l >> 4, cl = l & 15;
  const int m0 = blockIdx.x * 32;
  const int cb = w * 64;
  const f4_t fz = {0.f,0.f,0.f,0.f};
  f4_t acc[2][4];
#pragma unroll
  for (int fr = 0; fr < 2; fr++)
#pragma unroll
    for (int cf = 0; cf < 4; cf++) acc[fr][cf] = fz;
  const int r = tid >> 2, kq = tid & 3;
  for (int k0 = 0; k0 < K; k0 += 32){
    if (r < 32){
      bf8_t av = {0,0,0,0,0,0,0,0};
      if (m0 + r < NN) av = *(const bf8_t*)(A + (size_t)(m0 + r)*K + k0 + kq*8);
      *(bf8_t*)(&at[r*40 + kq*8]) = av;
    }
    __syncthreads();
    bf8_t bfr[4], afr[2];
#pragma unroll
    for (int cf = 0; cf < 4; cf++)
      bfr[cf] = *(const bf8_t*)(WT + (size_t)(cb + cf*16 + cl)*K + k0 + 8*g);
#pragma unroll
    for (int fr = 0; fr < 2; fr++)
      afr[fr] = *(const bf8_t*)(&at[(fr*16 + cl)*40 + 8*g]);
#pragma unroll
    for (int fr = 0; fr < 2; fr++)
#pragma unroll
      for (int cf = 0; cf < 4; cf++)
        acc[fr][cf] = __builtin_amdgcn_mfma_f32_16x16x32_bf16(afr[fr], bfr[cf], acc[fr][cf], 0, 0, 0);
    __syncthreads();
  }
#pragma unroll
  for (int fr = 0; fr < 2; fr++){
    float s1[4] = {0,0,0,0};
#pragma unroll
    for (int cf = 0; cf < 4; cf++){
      const int col = cb + cf*16 + cl;
      const float bv = bias[col], wv = gw2[col];
#pragma unroll
      for (int j = 0; j < 4; j++) s1[j] += fmaxf(acc[fr][cf][j] + bv, 0.f) * wv;
    }
#pragma unroll
    for (int j = 0; j < 4; j++){
      for (int m = 1; m < 16; m <<= 1) s1[j] += __shfl_xor(s1[j], m);
    }
    if (cl == 0){
#pragma unroll
      for (int j = 0; j < 4; j++) psum[w][fr*16 + 4*g + j] = s1[j];
    }
  }
  __syncthreads();
  if (tid < 32 && m0 + tid < NN)
    gatez[m0 + tid] = psum[0][tid] + psum[1][tid] + psum[2][tid] + psum[3][tid];
}

// ---------------- node update GEMM: residual + LayerNorm + pos update, agg staged on the fly --
__global__ __launch_bounds__(256, 2) void ln_gemm(
    short* hbf, const float* __restrict__ aggin, const short* __restrict__ WT,
    const float* __restrict__ bias, const float* __restrict__ gamma, const float* __restrict__ beta,
    float* hf32, float* __restrict__ aggz,
    float* __restrict__ cur_pos, float* __restrict__ pos_delta)
{
  __shared__ __align__(16) short at[32*40];
  __shared__ float psum[4][32], psq[4][32];
  __shared__ float mu_s[32], rs_s[32];
  const int K = 768;
  const int tid = threadIdx.x;
  const int w = tid >> 6, l = tid & 63;
  const int g = l >> 4, cl = l & 15;
  const int m0 = blockIdx.x * 32;
  const int cb = w * 64;
  const f4_t fz = {0.f,0.f,0.f,0.f};
  f4_t acc[2][4];
#pragma unroll
  for (int fr = 0; fr < 2; fr++)
#pragma unroll
    for (int cf = 0; cf < 4; cf++) acc[fr][cf] = fz;
  const int r = tid >> 2, kq = tid & 3;
  for (int k0 = 0; k0 < K; k0 += 32){
    if (r < 32){
      bf8_t av = {0,0,0,0,0,0,0,0};
      const int row = m0 + r;
      if (row < NN){
        if (k0 < 256){
          av = *(const bf8_t*)(hbf + (size_t)row*256 + k0 + kq*8);
        } else {
          const float* ap = aggin + (size_t)row*256 + (k0 & 255) + kq*8;
          float4 a = ((const float4*)ap)[0], b = ((const float4*)ap)[1];
          float x[8] = {a.x,a.y,a.z,a.w,b.x,b.y,b.z,b.w};
          short h[8];
#pragma unroll
          for (int j = 0; j < 8; j++) h[j] = f2b(x[j]);
          union { unsigned u[4]; bf8_t v; } o;
          if (k0 < 512){
#pragma unroll
            for (int j = 0; j < 4; j++)
              o.u[j] = ((unsigned)(unsigned short)h[2*j]) | (((unsigned)(unsigned short)h[2*j+1]) << 16);
          } else {
#pragma unroll
            for (int j = 0; j < 4; j++){
              const short l0 = f2b(x[2*j]   - b2f(h[2*j]));
              const short l1 = f2b(x[2*j+1] - b2f(h[2*j+1]));
              o.u[j] = ((unsigned)(unsigned short)l0) | (((unsigned)(unsigned short)l1) << 16);
            }
          }
          av = o.v;
        }
      }
      *(bf8_t*)(&at[r*40 + kq*8]) = av;
    }
    __syncthreads();
    bf8_t bfr[4], afr[2];
#pragma unroll
    for (int cf = 0; cf < 4; cf++)
      bfr[cf] = *(const bf8_t*)(WT + (size_t)(cb + cf*16 + cl)*K + k0 + 8*g);
#pragma unroll
    for (int fr = 0; fr < 2; fr++)
      afr[fr] = *(const bf8_t*)(&at[(fr*16 + cl)*40 + 8*g]);
#pragma unroll
    for (int fr = 0; fr < 2; fr++)
#pragma unroll
      for (int cf = 0; cf < 4; cf++)
        acc[fr][cf] = __builtin_amdgcn_mfma_f32_16x16x32_bf16(afr[fr], bfr[cf], acc[fr][cf], 0, 0, 0);
    __syncthreads();
  }
  // fused position update for this block's 32 rows (96 floats)
  if (tid < 96){
    const int i = m0*3 + tid;
    if (i < NN*3){ cur_pos[i] += pos_delta[i]; pos_delta[i] = 0.f; }
  }
#pragma unroll
  for (int fr = 0; fr < 2; fr++){
#pragma unroll
    for (int cf = 0; cf < 4; cf++){
      const int col = cb + cf*16 + cl;
      const float bv = bias[col];
#pragma unroll
      for (int j = 0; j < 4; j++){
        const int row = m0 + fr*16 + 4*g + j;
        const float hold = (row < NN) ? hf32[(size_t)row*256 + col] : 0.f;
        acc[fr][cf][j] = hold + fmaxf(acc[fr][cf][j] + bv, 0.f);
      }
    }
  }
#pragma unroll
  for (int fr = 0; fr < 2; fr++){
    float s1[4] = {0,0,0,0}, s2[4] = {0,0,0,0};
#pragma unroll
    for (int cf = 0; cf < 4; cf++)
#pragma unroll
      for (int j = 0; j < 4; j++){ float v = acc[fr][cf][j]; s1[j] += v; s2[j] += v*v; }
#pragma unroll
    for (int j = 0; j < 4; j++){
      for (int m = 1; m < 16; m <<= 1){ s1[j] += __shfl_xor(s1[j], m); s2[j] += __shfl_xor(s2[j], m); }
    }
    if (cl == 0){
#pragma unroll
      for (int j = 0; j < 4; j++){ psum[w][fr*16 + 4*g + j] = s1[j]; psq[w][fr*16 + 4*g + j] = s2[j]; }
    }
  }
  __syncthreads();
  if (tid < 32){
    float s = psum[0][tid] + psum[1][tid] + psum[2][tid] + psum[3][tid];
    float q = psq[0][tid] + psq[1][tid] + psq[2][tid] + psq[3][tid];
    float mu = s * (1.f/256.f);
    float var = q * (1.f/256.f) - mu*mu;
    mu_s[tid] = mu; rs_s[tid] = rsqrtf(var + 1e-5f);
  }
  __syncthreads();
#pragma unroll
  for (int fr = 0; fr < 2; fr++){
#pragma unroll
    for (int cf = 0; cf < 4; cf++){
      const int col = cb + cf*16 + cl;
#pragma unroll
      for (int j = 0; j < 4; j++){
        const int rl = fr*16 + 4*g + j;
        const int row = m0 + rl;
        if (row < NN){
          float v = (acc[fr][cf][j] - mu_s[rl]) * rs_s[rl] * gamma[col] + beta[col];
          hf32[(size_t)row*256 + col] = v;
          hbf[(size_t)row*256 + col] = f2b(v);
          aggz[(size_t)row*256 + col] = 0.f;   // re-zero for next layer (own rows only)
        }
      }
    }
  }
}

// ---------------- fully-fused per-layer edge kernel (dst-sorted, 64 edges, 4 waves) ----------------
// Round-5 structure + PINNED inline-asm src-gather prefetch at kernel top (compiler-proof T14).
__global__ __launch_bounds__(256, 4) void edge_kernel(
    const int* __restrict__ ssrc, const int* __restrict__ sdst, const int* __restrict__ sperm,
    const float* __restrict__ eattr,
    const float* __restrict__ cpos, const short* __restrict__ Abuf,
    const short* __restrict__ WeT, const float* __restrict__ b1,
    const short* __restrict__ W2T, const float* __restrict__ b2,
    const short* __restrict__ Wc1T, const float* __restrict__ bc1,
    const float* __restrict__ wc2, const float* __restrict__ bc2,
    float* __restrict__ agg, float* __restrict__ pos_delta)
{
  __shared__ __align__(16) short mt[ET*264];
  __shared__ int sidx[ET], didx[ET], pidx[ET];
  __shared__ float d2_s[ET];
  __shared__ float dir_s[ET][3];
  __shared__ float cpart[4][ET];
  short* at = mt;   // staging tile [ET][40], aliased; dead after GEMM0 reads
  const int tid = threadIdx.x;
  const int w = tid >> 6, l = tid & 63;
  const int g = l >> 4, cl = l & 15;
  const int e0 = blockIdx.x * ET;
  // PINNED T14 prefetch: issue all 8 src-row gathers before ANY barrier.
  // src index read directly from global (no LDS dependency). sched_barrier pins issue point.
  uint4 sv[8];
  {
    const int q = tid & 31;
#pragma unroll
    for (int i = 0; i < 8; i++){
      const int e = i*8 + (tid >> 5);
      const int s = ssrc[e0 + e];
      const short* p = Abuf + (size_t)s*512 + q*8;
      asm volatile("global_load_dwordx4 %0, %1, off" : "=v"(sv[i]) : "v"(p));
    }
    __builtin_amdgcn_sched_barrier(0);
  }
  // phase 0: indices + geometry
  if (tid < ET){
    const int p = e0 + tid;
    const int s = ssrc[p], d = sdst[p];
    sidx[tid] = s; didx[tid] = d; pidx[tid] = sperm[p];
    const float dx = cpos[d*3+0] - cpos[s*3+0];
    const float dy = cpos[d*3+1] - cpos[s*3+1];
    const float dz = cpos[d*3+2] - cpos[s*3+2];
    float d2 = dx*dx + dy*dy + dz*dz;
    d2 = fminf(d2, 1000.f);
    const float inv = rsqrtf(d2 + 1e-8f);
    d2_s[tid] = d2;
    dir_s[tid][0] = dx*inv; dir_s[tid][1] = dy*inv; dir_s[tid][2] = dz*inv;
  }
  __syncthreads();
  // stage ea_ext tile [ET][32] (stride 40) into at
  {
    const int e = tid >> 2, q = tid & 3;
    union { unsigned u[4]; bf8_t v; } o;
    o.u[0] = o.u[1] = o.u[2] = o.u[3] = 0u;
    if (q < 2){
      const float* ep = eattr + (size_t)pidx[e]*16 + q*8;
      float4 a = ((const float4*)ep)[0], b = ((const float4*)ep)[1];
      o.u[0] = cvt2(a.x, a.y); o.u[1] = cvt2(a.z, a.w);
      o.u[2] = cvt2(b.x, b.y); o.u[3] = cvt2(b.z, b.w);
    } else if (q == 2){
      const float d2 = d2_s[e];
      const short hi = f2b(d2);
      union { struct { short a, b; } s; unsigned u; } p;
      p.s.a = hi; p.s.b = f2b(d2 - b2f(hi));
      o.u[0] = p.u;
    }
    *(bf8_t*)(&at[e*40 + q*8]) = o.v;
  }
  __syncthreads();
  const int cb = w * 64;
  const f4_t fz = {0.f,0.f,0.f,0.f};
  // GEMM0: partial m1 = ea_ext @ WeT^T  (K=32, one k-step)
  f4_t a0[4][4];
#pragma unroll
  for (int fr = 0; fr < 4; fr++)
#pragma unroll
    for (int cf = 0; cf < 4; cf++) a0[fr][cf] = fz;
  {
    bf8_t bfr[4], afr[4];
#pragma unroll
    for (int cf = 0; cf < 4; cf++)
      bfr[cf] = *(const bf8_t*)(WeT + (size_t)(cb + cf*16 + cl)*32 + 8*g);
#pragma unroll
    for (int fr = 0; fr < 4; fr++)
      afr[fr] = *(const bf8_t*)(&at[(fr*16 + cl)*40 + 8*g]);
#pragma unroll
    for (int fr = 0; fr < 4; fr++)
#pragma unroll
      for (int cf = 0; cf < 4; cf++)
        a0[fr][cf] = __builtin_amdgcn_mfma_f32_16x16x32_bf16(afr[fr], bfr[cf], a0[fr][cf], 0, 0, 0);
  }
  __syncthreads();   // everyone done reading at before mt overwrite
  // epilogue0: mt = bf16(a0 + b1)  (no relu yet), packed converts
  {
#pragma unroll
    for (int cf = 0; cf < 4; cf++){
      const int col = cb + cf*16 + cl;
      const float b1v = b1[col];
#pragma unroll
      for (int fr = 0; fr < 4; fr++){
        const unsigned p01 = cvt2(a0[fr][cf][0] + b1v, a0[fr][cf][1] + b1v);
        const unsigned p23 = cvt2(a0[fr][cf][2] + b1v, a0[fr][cf][3] + b1v);
        short* base = &mt[(fr*16 + 4*g)*264 + col];
        base[0]   = (short)p01; base[264] = (short)(p01 >> 16);
        base[528] = (short)p23; base[792] = (short)(p23 >> 16);
      }
    }
  }
  __syncthreads();
  // phase 1b: mt = relu(mt + A[src] + A[dst]) — sv pinned-prefetched; wait here.
  {
    asm volatile("s_waitcnt vmcnt(0)" ::: "memory");
    __builtin_amdgcn_sched_barrier(0);
#pragma unroll
    for (int i = 0; i < 8; i++){
      const int u = i*256 + tid;
      const int e = u >> 5, q = u & 31;
      const uint4 dv = *(const uint4*)(Abuf + (size_t)didx[e]*512 + 256 + q*8);
      const uint4 mv = *(const uint4*)(&mt[e*264 + q*8]);
      uint4 o;
      {
        float2 a = up2(mv.x), b = up2(sv[i].x), c = up2(dv.x);
        o.x = cvt2(fmaxf(a.x + b.x + c.x, 0.f), fmaxf(a.y + b.y + c.y, 0.f));
      }{
        float2 a = up2(mv.y), b = up2(sv[i].y), c = up2(dv.y);
        o.y = cvt2(fmaxf(a.x + b.x + c.x, 0.f), fmaxf(a.y + b.y + c.y, 0.f));
      }{
        float2 a = up2(mv.z), b = up2(sv[i].z), c = up2(dv.z);
        o.z = cvt2(fmaxf(a.x + b.x + c.x, 0.f), fmaxf(a.y + b.y + c.y, 0.f));
      }{
        float2 a = up2(mv.w), b = up2(sv[i].w), c = up2(dv.w);
        o.w = cvt2(fmaxf(a.x + b.x + c.x, 0.f), fmaxf(a.y + b.y + c.y, 0.f));
      }
      *(uint4*)(&mt[e*264 + q*8]) = o;
    }
  }
  __syncthreads();
  // GEMM1: m = relu(m1 @ W2 + b2)
  f4_t a1[4][4];
#pragma unroll
  for (int fr = 0; fr < 4; fr++)
#pragma unroll
    for (int cf = 0; cf < 4; cf++) a1[fr][cf] = fz;
  for (int k0 = 0; k0 < 256; k0 += 32){
    bf8_t bfr[4], afr[4];
#pragma unroll
    for (int cf = 0; cf < 4; cf++)
      bfr[cf] = *(const bf8_t*)(W2T + (size_t)(cb + cf*16 + cl)*256 + k0 + 8*g);
#pragma unroll
    for (int fr = 0; fr < 4; fr++)
      afr[fr] = *(const bf8_t*)(&mt[(fr*16 + cl)*264 + k0 + 8*g]);
#pragma unroll
    for (int fr = 0; fr < 4; fr++)
#pragma unroll
      for (int cf = 0; cf < 4; cf++)
        a1[fr][cf] = __builtin_amdgcn_mfma_f32_16x16x32_bf16(afr[fr], bfr[cf], a1[fr][cf], 0, 0, 0);
  }
  __syncthreads();   // all waves done reading m1
  // epilogue1: m -> mt (bf16, relu), packed converts
  {
#pragma unroll
    for (int cf = 0; cf < 4; cf++){
      const int col = cb + cf*16 + cl;
      const float b2v = b2[col];
#pragma unroll
      for (int fr = 0; fr < 4; fr++){
        const unsigned p01 = cvt2(fmaxf(a1[fr][cf][0] + b2v, 0.f), fmaxf(a1[fr][cf][1] + b2v, 0.f));
        const unsigned p23 = cvt2(fmaxf(a1[fr][cf][2] + b2v, 0.f), fmaxf(a1[fr][cf][3] + b2v, 0.f));
        short* base = &mt[(fr*16 + 4*g)*264 + col];
        base[0]   = (short)p01; base[264] = (short)(p01 >> 16);
        base[528] = (short)p23; base[792] = (short)(p23 >> 16);
      }
    }
  }
  __syncthreads();
  // segmented column-sum of m into agg (sorted dst => few runs per block)
  {
    const int c = tid;
    float sum = 0.f;
    int prev = didx[0];
#pragma unroll 4
    for (int e = 0; e < ET; e++){
      const int d = didx[e];
      if (d != prev){
        atomicAdd(&agg[(size_t)prev*256 + c], sum);
        sum = 0.f; prev = d;
      }
      sum += b2f(mt[e*264 + c]);
    }
    atomicAdd(&agg[(size_t)prev*256 + c], sum);
  }
  // GEMM2: u = relu(m @ Wc1 + bc1); c = tanh(sum(u*wc2)+bc2)*0.1   (reads mt only; no barrier needed)
  f4_t a2[4][4];
#pragma unroll
  for (int fr = 0; fr < 4; fr++)
#pragma unroll
    for (int cf = 0; cf < 4; cf++) a2[fr][cf] = fz;
  for (int k0 = 0; k0 < 256; k0 += 32){
    bf8_t bfr[4], afr[4];
#pragma unroll
    for (int cf = 0; cf < 4; cf++)
      bfr[cf] = *(const bf8_t*)(Wc1T + (size_t)(cb + cf*16 + cl)*256 + k0 + 8*g);
#pragma unroll
    for (int fr = 0; fr < 4; fr++)
      afr[fr] = *(const bf8_t*)(&mt[(fr*16 + cl)*264 + k0 + 8*g]);
#pragma unroll
    for (int fr = 0; fr < 4; fr++)
#pragma unroll
      for (int cf = 0; cf < 4; cf++)
        a2[fr][cf] = __builtin_amdgcn_mfma_f32_16x16x32_bf16(afr[fr], bfr[cf], a2[fr][cf], 0, 0, 0);
  }
  {
    float bc1v[4], wc2v[4];
#pragma unroll
    for (int cf = 0; cf < 4; cf++){
      const int col = cb + cf*16 + cl;
      bc1v[cf] = bc1[col]; wc2v[cf] = wc2[col];
    }
#pragma unroll
    for (int fr = 0; fr < 4; fr++){
      float rs[4] = {0,0,0,0};
#pragma unroll
      for (int cf = 0; cf < 4; cf++)
#pragma unroll
        for (int j = 0; j < 4; j++)
          rs[j] += fmaxf(a2[fr][cf][j] + bc1v[cf], 0.f) * wc2v[cf];
#pragma unroll
      for (int j = 0; j < 4; j++){
        for (int m = 1; m < 16; m <<= 1) rs[j] += __shfl_xor(rs[j], m);
      }
      if (cl == 0){
#pragma unroll
        for (int j = 0; j < 4; j++) cpart[w][fr*16 + 4*g + j] = rs[j];
      }
    }
  }
  __syncthreads();
  if (tid < ET){
    const float cp = cpart[0][tid] + cpart[1][tid] + cpart[2][tid] + cpart[3][tid] + bc2[0];
    const float cc = tanhf(cp) * 0.1f;
    const int d = didx[tid];
    atomicAdd(&pos_delta[d*3+0], dir_s[tid][0]*cc);
    atomicAdd(&pos_delta[d*3+1], dir_s[tid][1]*cc);
    atomicAdd(&pos_delta[d*3+2], dir_s[tid][2]*cc);
  }
}

// ---------------- fusion gate/mix (one wave per node) ----------------
__global__ void fusion_mix(const float* __restrict__ gatez,
                           const float* __restrict__ gb2,
                           const float* __restrict__ s1p, const float* __restrict__ s2p,
                           const float* __restrict__ hef,
                           const float* __restrict__ pos,
                           float* hf32, short* __restrict__ hbf,
                           float* __restrict__ cur_pos, float* __restrict__ pos_delta,
                           float* __restrict__ agg)
{
  const int node = blockIdx.x * 4 + (threadIdx.x >> 6);
  const int l = threadIdx.x & 63;
  if (node >= NN) return;
  const float z = gatez[node] + gb2[0];
  const float gt = 1.f / (1.f + expf(-z));
  const float a = gt * s1p[0], b = (1.f - gt) * s2p[0];
#pragma unroll
  for (int k = 0; k < 4; k++){
    const int c = l + 64*k;
    const float hv = fmaxf(a*hf32[(size_t)node*256 + c] + b*hef[(size_t)node*256 + c], 0.f);
    hf32[(size_t)node*256 + c] = hv;
    hbf[(size_t)node*256 + c] = f2b(hv);
    agg[(size_t)node*256 + c] = 0.f;
  }
  if (l < 3){ cur_pos[node*3 + l] = pos[node*3 + l]; pos_delta[node*3 + l] = 0.f; }
}

// ---------------- final LN + head ----------------
__global__ void head_kernel(const float* __restrict__ hf32,
                            const float* __restrict__ fg, const float* __restrict__ fb,
                            const float* __restrict__ hw, const float* __restrict__ hbias,
                            float* __restrict__ out)
{
  const int node = blockIdx.x * 4 + (threadIdx.x >> 6);
  const int l = threadIdx.x & 63;
  if (node >= NN) return;
  float x[4], s = 0.f, q = 0.f;
#pragma unroll
  for (int k = 0; k < 4; k++){ x[k] = hf32[(size_t)node*256 + l + 64*k]; s += x[k]; q += x[k]*x[k]; }
#pragma unroll
  for (int m = 1; m < 64; m <<= 1){ s += __shfl_xor(s, m); q += __shfl_xor(q, m); }
  const float mu = s * (1.f/256.f);
  const float var = q * (1.f/256.f) - mu*mu;
  const float rs = rsqrtf(var + 1e-5f);
  float xn[4];
#pragma unroll
  for (int k = 0; k < 4; k++){ const int c = l + 64*k; xn[k] = (x[k]-mu)*rs*fg[c] + fb[c]; }
  for (int o = 0; o < 20; o++){
    float p = 0.f;
#pragma unroll
    for (int k = 0; k < 4; k++) p += xn[k] * hw[(l + 64*k)*20 + o];
#pragma unroll
    for (int m = 1; m < 64; m <<= 1) p += __shfl_xor(p, m);
    if (l == 0) out[node*20 + o] = p + hbias[o];
  }
}

extern "C" void kernel_launch(void* const* d_in, const int* in_sizes, int n_in,
                              void* d_out, int out_size, void* d_ws, size_t ws_size,
                              hipStream_t stream)
{
  (void)in_sizes; (void)n_in; (void)out_size; (void)ws_size;
  const float* x_struct = (const float*)d_in[0];
  const float* x_esm    = (const float*)d_in[1];
  const int*   eidx     = (const int*)d_in[2];
  const float* eattr    = (const float*)d_in[3];
  const float* pos      = (const float*)d_in[4];
  const float* struct_w = (const float*)d_in[5];
  const float* struct_b = (const float*)d_in[6];
  const float* esm_w    = (const float*)d_in[7];
  const float* esm_b    = (const float*)d_in[8];
  const float* gate_w1  = (const float*)d_in[9];
  const float* gate_b1  = (const float*)d_in[10];
  const float* gate_w2  = (const float*)d_in[11];
  const float* gate_b2  = (const float*)d_in[12];
  const float* s_scale  = (const float*)d_in[13];
  const float* e_scale  = (const float*)d_in[14];
  const float* edge_w1  = (const float*)d_in[15];
  const float* edge_b1  = (const float*)d_in[16];
  const float* edge_w2  = (const float*)d_in[17];
  const float* edge_b2  = (const float*)d_in[18];
  const float* coord_w1 = (const float*)d_in[19];
  const float* coord_b1 = (const float*)d_in[20];
  const float* coord_w2 = (const float*)d_in[21];
  const float* coord_b2 = (const float*)d_in[22];
  const float* node_w1  = (const float*)d_in[23];
  const float* node_b1  = (const float*)d_in[24];
  const float* ln_g     = (const float*)d_in[25];
  const float* ln_b     = (const float*)d_in[26];
  const float* fn_g     = (const float*)d_in[27];
  const float* fn_b     = (const float*)d_in[28];
  const float* head_w   = (const float*)d_in[29];
  const float* head_b   = (const float*)d_in[30];

  char* ws = (char*)d_ws;
  size_t off = 0;
  auto alloc = [&](size_t b){ size_t r = off; off += (b + 255) & ~(size_t)255; return r; };
  float* hf32 = (float*)(ws + alloc((size_t)NN*256*4));
  char* agghb = ws + alloc((size_t)NN*512*2);
  float* agg  = (float*)agghb;
  short* hb   = (short*)agghb;
  float* cpos = (float*)(ws + alloc((size_t)NN*3*4));
  float* pdel = (float*)(ws + alloc((size_t)NN*3*4));
  float* gatez= (float*)(ws + alloc((size_t)NN*4));
  short* hbf  = (short*)(ws + alloc((size_t)NN*256*2));
  char* AbufR = ws + alloc((size_t)NN*512*2);
  short* Abuf = (short*)AbufR;
  float* hef  = (float*)AbufR;
  int* hist   = (int*)(ws + alloc((size_t)NN*4));
  int* cursor = (int*)(ws + alloc((size_t)NN*4));
  int* ssrc   = (int*)(ws + alloc((size_t)EE*4));
  int* sdst   = (int*)(ws + alloc((size_t)EE*4));
  int* sperm  = (int*)(ws + alloc((size_t)EE*4));
  short* structT = (short*)(ws + alloc(256*64*2));
  short* esmT    = (short*)(ws + alloc(256*1280*2));
  short* gateT   = (short*)(ws + alloc(256*512*2));
  short* EW1T    = (short*)(ws + alloc((size_t)4*512*256*2));
  short* W2T     = (short*)(ws + alloc((size_t)4*256*256*2));
  short* Wc1T    = (short*)(ws + alloc((size_t)4*256*256*2));
  short* NW1T    = (short*)(ws + alloc((size_t)4*256*768*2));
  short* WeT     = (short*)(ws + alloc((size_t)4*256*32*2));

  // edge sort by dst (once per launch)
  zero_hist<<<dim3(40), 256, 0, stream>>>(hist);
  count_k<<<dim3(1250), 256, 0, stream>>>(eidx, hist);
  scan_k<<<dim3(1), 256, 0, stream>>>(hist, cursor);
  scatter_k<<<dim3(1250), 256, 0, stream>>>(eidx, cursor, ssrc, sdst, sperm);

  prep_fusion<<<dim3(1856), 256, 0, stream>>>(struct_w, esm_w, gate_w1, structT, esmT, gateT);
  prep_layer<<<dim3(1824, 4), 256, 0, stream>>>(edge_w1, edge_w2, coord_w1, node_w1,
                                                EW1T, W2T, Wc1T, NW1T, WeT);

  gemm_bf16<false,float,32><<<dim3(313,1), 256, 0, stream>>>(x_struct, 64, 64, structT, struct_b, NN,
                                                             hf32, 256, hb, 512);
  gemm_bf16<false,float,32><<<dim3(313,1), 256, 0, stream>>>(x_esm, 1280, 1280, esmT, esm_b, NN,
                                                             hef, 256, hb + 256, 512);
  gate_gemm<<<dim3(313), 256, 0, stream>>>(hb, gateT, gate_b1, gate_w2, gatez);
  fusion_mix<<<dim3(2500), 256, 0, stream>>>(gatez, gate_b2, s_scale, e_scale, hef, pos,
                                             hf32, hbf, cpos, pdel, agg);
  for (int i = 0; i < 4; i++){
    gemm_bf16<false,short,32><<<dim3(313,2), 256, 0, stream>>>(hbf, 256, 256,
                                                               EW1T + (size_t)i*512*256, nullptr, NN,
                                                               nullptr, 0, Abuf, 512);
    edge_kernel<<<dim3(EE/ET), 256, 0, stream>>>(ssrc, sdst, sperm, eattr, cpos, Abuf,
        WeT + (size_t)i*256*32, edge_b1 + (size_t)i*256,
        W2T + (size_t)i*256*256, edge_b2 + (size_t)i*256,
        Wc1T + (size_t)i*256*256, coord_b1 + (size_t)i*256,
        coord_w2 + (size_t)i*256, coord_b2 + i,
        agg, pdel);
    ln_gemm<<<dim3(313), 256, 0, stream>>>(hbf, agg, NW1T + (size_t)i*256*768,
                                           node_b1 + (size_t)i*256,
                                           ln_g + (size_t)i*256, ln_b + (size_t)i*256,
                                           hf32, agg, cpos, pdel);
  }
  head_kernel<<<dim3(2500), 256, 0, stream>>>(hf32, fn_g, fn_b, head_w, head_b, (float*)d_out);
}

// Round 14
// 1574.750 us; speedup vs baseline: 1.0293x; 1.0293x over previous
//
#include <hip/hip_runtime.h>
#include <hip/hip_bf16.h>

#define NN 10000
#define EE 320000
#define ET 64   // edges per block in edge_kernel

typedef __attribute__((ext_vector_type(8))) short bf8_t;   // 8 bf16 (4 VGPR)
typedef __attribute__((ext_vector_type(4))) short s4_t;
typedef __attribute__((ext_vector_type(4))) float f4_t;

__device__ __forceinline__ float b2f(short b){
  union { unsigned u; float f; } v; v.u = ((unsigned)(unsigned short)b) << 16; return v.f;
}
__device__ __forceinline__ short f2b(float f){
  union { float f; unsigned u; } v; v.f = f;
  unsigned r = (v.u + 0x7fffu + ((v.u >> 16) & 1u)) >> 16;
  return (short)r;
}
// native packed f32->bf16 (RNE), 1 inst for 2 elements
__device__ __forceinline__ unsigned cvt2(float lo, float hi){
  unsigned r; asm("v_cvt_pk_bf16_f32 %0, %1, %2" : "=v"(r) : "v"(lo), "v"(hi)); return r;
}
// unpack u32 (2 bf16) -> 2 f32
__device__ __forceinline__ float2 up2(unsigned u){
  union { unsigned v; float f; } a, b;
  a.v = u << 16; b.v = u & 0xffff0000u;
  float2 r; r.x = a.f; r.y = b.f; return r;
}

// staging loaders: 8 contiguous elements -> bf16x8
__device__ __forceinline__ bf8_t load8(const short* p){ return *(const bf8_t*)p; }
__device__ __forceinline__ bf8_t load8(const float* p){
  float4 a = ((const float4*)p)[0], b = ((const float4*)p)[1];
  union { unsigned u[4]; bf8_t v; } o;
  o.u[0] = cvt2(a.x, a.y); o.u[1] = cvt2(a.z, a.w);
  o.u[2] = cvt2(b.x, b.y); o.u[3] = cvt2(b.z, b.w);
  return o.v;
}

// ================= counting sort of edges by dst =================
__global__ void zero_hist(int* __restrict__ hist){
  int i = blockIdx.x * 256 + threadIdx.x;
  if (i < NN) hist[i] = 0;
}
__global__ void count_k(const int* __restrict__ eidx, int* __restrict__ hist){
  int e = blockIdx.x * 256 + threadIdx.x;
  if (e < EE) atomicAdd(&hist[eidx[EE + e]], 1);
}
__global__ void scan_k(const int* __restrict__ hist, int* __restrict__ cursor){
  __shared__ int partsum[256];
  const int tid = threadIdx.x;
  const int base = tid * 40;
  int local[40]; int s = 0;
  for (int j = 0; j < 40; j++){
    int b = base + j; int v = (b < NN) ? hist[b] : 0;
    local[j] = s; s += v;
  }
  partsum[tid] = s;
  __syncthreads();
  if (tid == 0){
    int acc = 0;
    for (int i = 0; i < 256; i++){ int t = partsum[i]; partsum[i] = acc; acc += t; }
  }
  __syncthreads();
  const int off = partsum[tid];
  for (int j = 0; j < 40; j++){
    int b = base + j;
    if (b < NN) cursor[b] = off + local[j];
  }
}
__global__ void scatter_k(const int* __restrict__ eidx, int* __restrict__ cursor,
                          int* __restrict__ ssrc, int* __restrict__ sdst, int* __restrict__ sperm){
  int e = blockIdx.x * 256 + threadIdx.x;
  if (e >= EE) return;
  int d = eidx[EE + e];
  int p = atomicAdd(&cursor[d], 1);
  ssrc[p] = eidx[e]; sdst[p] = d; sperm[p] = e;
}

// ---------------- weight transpose+convert: fusion weights ----------------
__global__ void prep_fusion(const float* __restrict__ sw, const float* __restrict__ ew,
                            const float* __restrict__ gw,
                            short* __restrict__ structT, short* __restrict__ esmT,
                            short* __restrict__ gateT){
  int idx = blockIdx.x * 256 + threadIdx.x;
  if (idx < 256*64){ int o = idx/64, k = idx - o*64; structT[idx] = f2b(sw[k*256+o]); return; }
  idx -= 256*64;
  if (idx < 256*1280){ int o = idx/1280, k = idx - o*1280; esmT[idx] = f2b(ew[k*256+o]); return; }
  idx -= 256*1280;
  if (idx < 256*512){ int o = idx/512, k = idx - o*512; gateT[idx] = f2b(gw[k*256+o]); return; }
}

// ---------------- per-layer weight prep, all 4 layers in one launch (blockIdx.y = layer) ------
__global__ void prep_layer(const float* __restrict__ ew1_0, const float* __restrict__ ew2_0,
                           const float* __restrict__ cw1_0, const float* __restrict__ nw1_0,
                           short* __restrict__ EW1T_0, short* __restrict__ W2T_0,
                           short* __restrict__ Wc1T_0, short* __restrict__ NW1T_0,
                           short* __restrict__ WeT_0){
  const int li = blockIdx.y;
  const float* ew1 = ew1_0 + (size_t)li*529*256;
  const float* ew2 = ew2_0 + (size_t)li*256*256;
  const float* cw1 = cw1_0 + (size_t)li*256*256;
  const float* nw1 = nw1_0 + (size_t)li*512*256;
  short* EW1T = EW1T_0 + (size_t)li*512*256;
  short* W2T  = W2T_0  + (size_t)li*256*256;
  short* Wc1T = Wc1T_0 + (size_t)li*256*256;
  short* NW1T = NW1T_0 + (size_t)li*256*768;
  short* WeT  = WeT_0  + (size_t)li*256*32;
  int idx = blockIdx.x * 256 + threadIdx.x;
  if (idx < 512*256){
    int o = idx >> 8, k = idx & 255;
    float v = (o < 256) ? ew1[k*256 + o] : ew1[(256 + k)*256 + (o - 256)];
    EW1T[idx] = f2b(v); return;
  } idx -= 512*256;
  if (idx < 65536){ int o = idx >> 8, k = idx & 255; W2T[idx] = f2b(ew2[k*256+o]); return; } idx -= 65536;
  if (idx < 65536){ int o = idx >> 8, k = idx & 255; Wc1T[idx] = f2b(cw1[k*256+o]); return; } idx -= 65536;
  if (idx < 256*768){
    int o = idx/768, k = idx - o*768;
    int kk = (k < 512) ? k : (k - 256);
    NW1T[idx] = f2b(nw1[kk*256 + o]); return;
  } idx -= 256*768;
  if (idx < 256*32){
    int o = idx >> 5, k = idx & 31;
    float v = (k < 16) ? ew1[(513 + k)*256 + o] : ((k < 18) ? ew1[512*256 + o] : 0.f);
    WeT[idx] = f2b(v);
  }
}

// ---------------- generic bf16 MFMA GEMM, MT rows per block ----------------
template<bool RELU, typename AT, int MT>
__global__ __launch_bounds__(256, 2) void gemm_bf16(
    const AT* __restrict__ A, const int K, const int lda, const short* __restrict__ WT,
    const float* __restrict__ bias, const int M,
    float* __restrict__ outF, const int ldf,
    short* __restrict__ outB, const int ldb)
{
  __shared__ __align__(16) short at[MT*40];
  const int tid = threadIdx.x;
  const int w = tid >> 6, l = tid & 63;
  const int g = l >> 4, cl = l & 15;
  const int m0 = blockIdx.x * MT;
  const int cb = blockIdx.y * 256 + w * 64;
  const f4_t fz = {0.f, 0.f, 0.f, 0.f};
  f4_t acc[MT/16][4];
#pragma unroll
  for (int fr = 0; fr < MT/16; fr++)
#pragma unroll
    for (int cf = 0; cf < 4; cf++) acc[fr][cf] = fz;
  const int r = tid >> 2, kq = tid & 3;
  for (int k0 = 0; k0 < K; k0 += 32){
    if (r < MT){
      bf8_t av = {0,0,0,0,0,0,0,0};
      if (m0 + r < M) av = load8(A + (size_t)(m0 + r)*lda + k0 + kq*8);
      *(bf8_t*)(&at[r*40 + kq*8]) = av;
    }
    __syncthreads();
    bf8_t bfr[4], afr[MT/16];
#pragma unroll
    for (int cf = 0; cf < 4; cf++)
      bfr[cf] = *(const bf8_t*)(WT + (size_t)(cb + cf*16 + cl)*K + k0 + 8*g);
#pragma unroll
    for (int fr = 0; fr < MT/16; fr++)
      afr[fr] = *(const bf8_t*)(&at[(fr*16 + cl)*40 + 8*g]);
#pragma unroll
    for (int fr = 0; fr < MT/16; fr++)
#pragma unroll
      for (int cf = 0; cf < 4; cf++)
        acc[fr][cf] = __builtin_amdgcn_mfma_f32_16x16x32_bf16(afr[fr], bfr[cf], acc[fr][cf], 0, 0, 0);
    __syncthreads();
  }
#pragma unroll
  for (int fr = 0; fr < MT/16; fr++){
#pragma unroll
    for (int cf = 0; cf < 4; cf++){
      const int col = cb + cf*16 + cl;
      const float bv = bias ? bias[col] : 0.f;
#pragma unroll
      for (int j = 0; j < 4; j++){
        const int row = m0 + fr*16 + 4*g + j;
        if (row < M){
          float v = acc[fr][cf][j] + bv;
          if (RELU) v = fmaxf(v, 0.f);
          if (outF) outF[(size_t)row*ldf + col] = v;
          if (outB) outB[(size_t)row*ldb + col] = f2b(v);
        }
      }
    }
  }
}

// ---------------- gate GEMM with fused dot-product reduction (32 rows/block) ----------------
__global__ __launch_bounds__(256, 2) void gate_gemm(
    const short* __restrict__ A, const short* __restrict__ WT,
    const float* __restrict__ bias, const float* __restrict__ gw2,
    float* __restrict__ gatez)
{
  __shared__ __align__(16) short at[32*40];
  __shared__ float psum[4][32];
  const int K = 512;
  const int tid = threadIdx.x;
  const int w = tid >> 6, l = tid & 63;
  const int g = l >> 4, cl = l & 15;
  const int m0 = blockIdx.x * 32;
  const int cb = w * 64;
  const f4_t fz = {0.f,0.f,0.f,0.f};
  f4_t acc[2][4];
#pragma unroll
  for (int fr = 0; fr < 2; fr++)
#pragma unroll
    for (int cf = 0; cf < 4; cf++) acc[fr][cf] = fz;
  const int r = tid >> 2, kq = tid & 3;
  for (int k0 = 0; k0 < K; k0 += 32){
    if (r < 32){
      bf8_t av = {0,0,0,0,0,0,0,0};
      if (m0 + r < NN) av = *(const bf8_t*)(A + (size_t)(m0 + r)*K + k0 + kq*8);
      *(bf8_t*)(&at[r*40 + kq*8]) = av;
    }
    __syncthreads();
    bf8_t bfr[4], afr[2];
#pragma unroll
    for (int cf = 0; cf < 4; cf++)
      bfr[cf] = *(const bf8_t*)(WT + (size_t)(cb + cf*16 + cl)*K + k0 + 8*g);
#pragma unroll
    for (int fr = 0; fr < 2; fr++)
      afr[fr] = *(const bf8_t*)(&at[(fr*16 + cl)*40 + 8*g]);
#pragma unroll
    for (int fr = 0; fr < 2; fr++)
#pragma unroll
      for (int cf = 0; cf < 4; cf++)
        acc[fr][cf] = __builtin_amdgcn_mfma_f32_16x16x32_bf16(afr[fr], bfr[cf], acc[fr][cf], 0, 0, 0);
    __syncthreads();
  }
#pragma unroll
  for (int fr = 0; fr < 2; fr++){
    float s1[4] = {0,0,0,0};
#pragma unroll
    for (int cf = 0; cf < 4; cf++){
      const int col = cb + cf*16 + cl;
      const float bv = bias[col], wv = gw2[col];
#pragma unroll
      for (int j = 0; j < 4; j++) s1[j] += fmaxf(acc[fr][cf][j] + bv, 0.f) * wv;
    }
#pragma unroll
    for (int j = 0; j < 4; j++){
      for (int m = 1; m < 16; m <<= 1) s1[j] += __shfl_xor(s1[j], m);
    }
    if (cl == 0){
#pragma unroll
      for (int j = 0; j < 4; j++) psum[w][fr*16 + 4*g + j] = s1[j];
    }
  }
  __syncthreads();
  if (tid < 32 && m0 + tid < NN)
    gatez[m0 + tid] = psum[0][tid] + psum[1][tid] + psum[2][tid] + psum[3][tid];
}

// ---------------- node update GEMM: residual + LayerNorm + pos update, agg staged on the fly --
__global__ __launch_bounds__(256, 2) void ln_gemm(
    short* hbf, const float* __restrict__ aggin, const short* __restrict__ WT,
    const float* __restrict__ bias, const float* __restrict__ gamma, const float* __restrict__ beta,
    float* hf32, float* __restrict__ aggz,
    float* __restrict__ cur_pos, float* __restrict__ pos_delta)
{
  __shared__ __align__(16) short at[32*40];
  __shared__ float psum[4][32], psq[4][32];
  __shared__ float mu_s[32], rs_s[32];
  const int K = 768;
  const int tid = threadIdx.x;
  const int w = tid >> 6, l = tid & 63;
  const int g = l >> 4, cl = l & 15;
  const int m0 = blockIdx.x * 32;
  const int cb = w * 64;
  const f4_t fz = {0.f,0.f,0.f,0.f};
  f4_t acc[2][4];
#pragma unroll
  for (int fr = 0; fr < 2; fr++)
#pragma unroll
    for (int cf = 0; cf < 4; cf++) acc[fr][cf] = fz;
  const int r = tid >> 2, kq = tid & 3;
  for (int k0 = 0; k0 < K; k0 += 32){
    if (r < 32){
      bf8_t av = {0,0,0,0,0,0,0,0};
      const int row = m0 + r;
      if (row < NN){
        if (k0 < 256){
          av = *(const bf8_t*)(hbf + (size_t)row*256 + k0 + kq*8);
        } else {
          const float* ap = aggin + (size_t)row*256 + (k0 & 255) + kq*8;
          float4 a = ((const float4*)ap)[0], b = ((const float4*)ap)[1];
          float x[8] = {a.x,a.y,a.z,a.w,b.x,b.y,b.z,b.w};
          short h[8];
#pragma unroll
          for (int j = 0; j < 8; j++) h[j] = f2b(x[j]);
          union { unsigned u[4]; bf8_t v; } o;
          if (k0 < 512){
#pragma unroll
            for (int j = 0; j < 4; j++)
              o.u[j] = ((unsigned)(unsigned short)h[2*j]) | (((unsigned)(unsigned short)h[2*j+1]) << 16);
          } else {
#pragma unroll
            for (int j = 0; j < 4; j++){
              const short l0 = f2b(x[2*j]   - b2f(h[2*j]));
              const short l1 = f2b(x[2*j+1] - b2f(h[2*j+1]));
              o.u[j] = ((unsigned)(unsigned short)l0) | (((unsigned)(unsigned short)l1) << 16);
            }
          }
          av = o.v;
        }
      }
      *(bf8_t*)(&at[r*40 + kq*8]) = av;
    }
    __syncthreads();
    bf8_t bfr[4], afr[2];
#pragma unroll
    for (int cf = 0; cf < 4; cf++)
      bfr[cf] = *(const bf8_t*)(WT + (size_t)(cb + cf*16 + cl)*K + k0 + 8*g);
#pragma unroll
    for (int fr = 0; fr < 2; fr++)
      afr[fr] = *(const bf8_t*)(&at[(fr*16 + cl)*40 + 8*g]);
#pragma unroll
    for (int fr = 0; fr < 2; fr++)
#pragma unroll
      for (int cf = 0; cf < 4; cf++)
        acc[fr][cf] = __builtin_amdgcn_mfma_f32_16x16x32_bf16(afr[fr], bfr[cf], acc[fr][cf], 0, 0, 0);
    __syncthreads();
  }
  // fused position update for this block's 32 rows (96 floats)
  if (tid < 96){
    const int i = m0*3 + tid;
    if (i < NN*3){ cur_pos[i] += pos_delta[i]; pos_delta[i] = 0.f; }
  }
#pragma unroll
  for (int fr = 0; fr < 2; fr++){
#pragma unroll
    for (int cf = 0; cf < 4; cf++){
      const int col = cb + cf*16 + cl;
      const float bv = bias[col];
#pragma unroll
      for (int j = 0; j < 4; j++){
        const int row = m0 + fr*16 + 4*g + j;
        const float hold = (row < NN) ? hf32[(size_t)row*256 + col] : 0.f;
        acc[fr][cf][j] = hold + fmaxf(acc[fr][cf][j] + bv, 0.f);
      }
    }
  }
#pragma unroll
  for (int fr = 0; fr < 2; fr++){
    float s1[4] = {0,0,0,0}, s2[4] = {0,0,0,0};
#pragma unroll
    for (int cf = 0; cf < 4; cf++)
#pragma unroll
      for (int j = 0; j < 4; j++){ float v = acc[fr][cf][j]; s1[j] += v; s2[j] += v*v; }
#pragma unroll
    for (int j = 0; j < 4; j++){
      for (int m = 1; m < 16; m <<= 1){ s1[j] += __shfl_xor(s1[j], m); s2[j] += __shfl_xor(s2[j], m); }
    }
    if (cl == 0){
#pragma unroll
      for (int j = 0; j < 4; j++){ psum[w][fr*16 + 4*g + j] = s1[j]; psq[w][fr*16 + 4*g + j] = s2[j]; }
    }
  }
  __syncthreads();
  if (tid < 32){
    float s = psum[0][tid] + psum[1][tid] + psum[2][tid] + psum[3][tid];
    float q = psq[0][tid] + psq[1][tid] + psq[2][tid] + psq[3][tid];
    float mu = s * (1.f/256.f);
    float var = q * (1.f/256.f) - mu*mu;
    mu_s[tid] = mu; rs_s[tid] = rsqrtf(var + 1e-5f);
  }
  __syncthreads();
#pragma unroll
  for (int fr = 0; fr < 2; fr++){
#pragma unroll
    for (int cf = 0; cf < 4; cf++){
      const int col = cb + cf*16 + cl;
#pragma unroll
      for (int j = 0; j < 4; j++){
        const int rl = fr*16 + 4*g + j;
        const int row = m0 + rl;
        if (row < NN){
          float v = (acc[fr][cf][j] - mu_s[rl]) * rs_s[rl] * gamma[col] + beta[col];
          hf32[(size_t)row*256 + col] = v;
          hbf[(size_t)row*256 + col] = f2b(v);
          aggz[(size_t)row*256 + col] = 0.f;   // re-zero for next layer (own rows only)
        }
      }
    }
  }
}

// ---------------- fully-fused per-layer edge kernel (dst-sorted, 64 edges, 4 waves) ----------------
// Round-5/12 structure: compiler-scheduled gathers (pinned prefetch measured-rejected, round 13).
__global__ __launch_bounds__(256, 4) void edge_kernel(
    const int* __restrict__ ssrc, const int* __restrict__ sdst, const int* __restrict__ sperm,
    const float* __restrict__ eattr,
    const float* __restrict__ cpos, const short* __restrict__ Abuf,
    const short* __restrict__ WeT, const float* __restrict__ b1,
    const short* __restrict__ W2T, const float* __restrict__ b2,
    const short* __restrict__ Wc1T, const float* __restrict__ bc1,
    const float* __restrict__ wc2, const float* __restrict__ bc2,
    float* __restrict__ agg, float* __restrict__ pos_delta)
{
  __shared__ __align__(16) short mt[ET*264];
  __shared__ int sidx[ET], didx[ET], pidx[ET];
  __shared__ float d2_s[ET];
  __shared__ float dir_s[ET][3];
  __shared__ float cpart[4][ET];
  short* at = mt;   // staging tile [ET][40], aliased; dead after GEMM0 reads
  const int tid = threadIdx.x;
  const int w = tid >> 6, l = tid & 63;
  const int g = l >> 4, cl = l & 15;
  const int e0 = blockIdx.x * ET;
  // phase 0: indices + geometry
  if (tid < ET){
    const int p = e0 + tid;
    const int s = ssrc[p], d = sdst[p];
    sidx[tid] = s; didx[tid] = d; pidx[tid] = sperm[p];
    const float dx = cpos[d*3+0] - cpos[s*3+0];
    const float dy = cpos[d*3+1] - cpos[s*3+1];
    const float dz = cpos[d*3+2] - cpos[s*3+2];
    float d2 = dx*dx + dy*dy + dz*dz;
    d2 = fminf(d2, 1000.f);
    const float inv = rsqrtf(d2 + 1e-8f);
    d2_s[tid] = d2;
    dir_s[tid][0] = dx*inv; dir_s[tid][1] = dy*inv; dir_s[tid][2] = dz*inv;
  }
  __syncthreads();
  // stage ea_ext tile [ET][32] (stride 40) into at
  {
    const int e = tid >> 2, q = tid & 3;
    union { unsigned u[4]; bf8_t v; } o;
    o.u[0] = o.u[1] = o.u[2] = o.u[3] = 0u;
    if (q < 2){
      const float* ep = eattr + (size_t)pidx[e]*16 + q*8;
      float4 a = ((const float4*)ep)[0], b = ((const float4*)ep)[1];
      o.u[0] = cvt2(a.x, a.y); o.u[1] = cvt2(a.z, a.w);
      o.u[2] = cvt2(b.x, b.y); o.u[3] = cvt2(b.z, b.w);
    } else if (q == 2){
      const float d2 = d2_s[e];
      const short hi = f2b(d2);
      union { struct { short a, b; } s; unsigned u; } p;
      p.s.a = hi; p.s.b = f2b(d2 - b2f(hi));
      o.u[0] = p.u;
    }
    *(bf8_t*)(&at[e*40 + q*8]) = o.v;
  }
  __syncthreads();
  const int cb = w * 64;
  const f4_t fz = {0.f,0.f,0.f,0.f};
  // GEMM0: partial m1 = ea_ext @ WeT^T  (K=32, one k-step)
  f4_t a0[4][4];
#pragma unroll
  for (int fr = 0; fr < 4; fr++)
#pragma unroll
    for (int cf = 0; cf < 4; cf++) a0[fr][cf] = fz;
  {
    bf8_t bfr[4], afr[4];
#pragma unroll
    for (int cf = 0; cf < 4; cf++)
      bfr[cf] = *(const bf8_t*)(WeT + (size_t)(cb + cf*16 + cl)*32 + 8*g);
#pragma unroll
    for (int fr = 0; fr < 4; fr++)
      afr[fr] = *(const bf8_t*)(&at[(fr*16 + cl)*40 + 8*g]);
#pragma unroll
    for (int fr = 0; fr < 4; fr++)
#pragma unroll
      for (int cf = 0; cf < 4; cf++)
        a0[fr][cf] = __builtin_amdgcn_mfma_f32_16x16x32_bf16(afr[fr], bfr[cf], a0[fr][cf], 0, 0, 0);
  }
  __syncthreads();   // everyone done reading at before mt overwrite
  // epilogue0: mt = bf16(a0 + b1)  (no relu yet), packed converts
  {
#pragma unroll
    for (int cf = 0; cf < 4; cf++){
      const int col = cb + cf*16 + cl;
      const float b1v = b1[col];
#pragma unroll
      for (int fr = 0; fr < 4; fr++){
        const unsigned p01 = cvt2(a0[fr][cf][0] + b1v, a0[fr][cf][1] + b1v);
        const unsigned p23 = cvt2(a0[fr][cf][2] + b1v, a0[fr][cf][3] + b1v);
        short* base = &mt[(fr*16 + 4*g)*264 + col];
        base[0]   = (short)p01; base[264] = (short)(p01 >> 16);
        base[528] = (short)p23; base[792] = (short)(p23 >> 16);
      }
    }
  }
  __syncthreads();
  // phase 1b: mt = relu(mt + A[src] + A[dst])  — u32 granules, compiler-interleaved gathers
  {
    uint4 sv[8];
#pragma unroll
    for (int i = 0; i < 8; i++){
      const int u = i*256 + tid;
      const int e = u >> 5, q = u & 31;
      sv[i] = *(const uint4*)(Abuf + (size_t)sidx[e]*512 + q*8);
    }
#pragma unroll
    for (int i = 0; i < 8; i++){
      const int u = i*256 + tid;
      const int e = u >> 5, q = u & 31;
      const uint4 dv = *(const uint4*)(Abuf + (size_t)didx[e]*512 + 256 + q*8);
      const uint4 mv = *(const uint4*)(&mt[e*264 + q*8]);
      uint4 o;
      {
        float2 a = up2(mv.x), b = up2(sv[i].x), c = up2(dv.x);
        o.x = cvt2(fmaxf(a.x + b.x + c.x, 0.f), fmaxf(a.y + b.y + c.y, 0.f));
      }{
        float2 a = up2(mv.y), b = up2(sv[i].y), c = up2(dv.y);
        o.y = cvt2(fmaxf(a.x + b.x + c.x, 0.f), fmaxf(a.y + b.y + c.y, 0.f));
      }{
        float2 a = up2(mv.z), b = up2(sv[i].z), c = up2(dv.z);
        o.z = cvt2(fmaxf(a.x + b.x + c.x, 0.f), fmaxf(a.y + b.y + c.y, 0.f));
      }{
        float2 a = up2(mv.w), b = up2(sv[i].w), c = up2(dv.w);
        o.w = cvt2(fmaxf(a.x + b.x + c.x, 0.f), fmaxf(a.y + b.y + c.y, 0.f));
      }
      *(uint4*)(&mt[e*264 + q*8]) = o;
    }
  }
  __syncthreads();
  // GEMM1: m = relu(m1 @ W2 + b2)
  f4_t a1[4][4];
#pragma unroll
  for (int fr = 0; fr < 4; fr++)
#pragma unroll
    for (int cf = 0; cf < 4; cf++) a1[fr][cf] = fz;
  for (int k0 = 0; k0 < 256; k0 += 32){
    bf8_t bfr[4], afr[4];
#pragma unroll
    for (int cf = 0; cf < 4; cf++)
      bfr[cf] = *(const bf8_t*)(W2T + (size_t)(cb + cf*16 + cl)*256 + k0 + 8*g);
#pragma unroll
    for (int fr = 0; fr < 4; fr++)
      afr[fr] = *(const bf8_t*)(&mt[(fr*16 + cl)*264 + k0 + 8*g]);
#pragma unroll
    for (int fr = 0; fr < 4; fr++)
#pragma unroll
      for (int cf = 0; cf < 4; cf++)
        a1[fr][cf] = __builtin_amdgcn_mfma_f32_16x16x32_bf16(afr[fr], bfr[cf], a1[fr][cf], 0, 0, 0);
  }
  __syncthreads();   // all waves done reading m1
  // epilogue1: m -> mt (bf16, relu), packed converts
  {
#pragma unroll
    for (int cf = 0; cf < 4; cf++){
      const int col = cb + cf*16 + cl;
      const float b2v = b2[col];
#pragma unroll
      for (int fr = 0; fr < 4; fr++){
        const unsigned p01 = cvt2(fmaxf(a1[fr][cf][0] + b2v, 0.f), fmaxf(a1[fr][cf][1] + b2v, 0.f));
        const unsigned p23 = cvt2(fmaxf(a1[fr][cf][2] + b2v, 0.f), fmaxf(a1[fr][cf][3] + b2v, 0.f));
        short* base = &mt[(fr*16 + 4*g)*264 + col];
        base[0]   = (short)p01; base[264] = (short)(p01 >> 16);
        base[528] = (short)p23; base[792] = (short)(p23 >> 16);
      }
    }
  }
  __syncthreads();
  // segmented column-sum of m into agg (sorted dst => few runs per block)
  {
    const int c = tid;
    float sum = 0.f;
    int prev = didx[0];
#pragma unroll 4
    for (int e = 0; e < ET; e++){
      const int d = didx[e];
      if (d != prev){
        atomicAdd(&agg[(size_t)prev*256 + c], sum);
        sum = 0.f; prev = d;
      }
      sum += b2f(mt[e*264 + c]);
    }
    atomicAdd(&agg[(size_t)prev*256 + c], sum);
  }
  // GEMM2: u = relu(m @ Wc1 + bc1); c = tanh(sum(u*wc2)+bc2)*0.1   (reads mt only; no barrier needed)
  f4_t a2[4][4];
#pragma unroll
  for (int fr = 0; fr < 4; fr++)
#pragma unroll
    for (int cf = 0; cf < 4; cf++) a2[fr][cf] = fz;
  for (int k0 = 0; k0 < 256; k0 += 32){
    bf8_t bfr[4], afr[4];
#pragma unroll
    for (int cf = 0; cf < 4; cf++)
      bfr[cf] = *(const bf8_t*)(Wc1T + (size_t)(cb + cf*16 + cl)*256 + k0 + 8*g);
#pragma unroll
    for (int fr = 0; fr < 4; fr++)
      afr[fr] = *(const bf8_t*)(&mt[(fr*16 + cl)*264 + k0 + 8*g]);
#pragma unroll
    for (int fr = 0; fr < 4; fr++)
#pragma unroll
      for (int cf = 0; cf < 4; cf++)
        a2[fr][cf] = __builtin_amdgcn_mfma_f32_16x16x32_bf16(afr[fr], bfr[cf], a2[fr][cf], 0, 0, 0);
  }
  {
    float bc1v[4], wc2v[4];
#pragma unroll
    for (int cf = 0; cf < 4; cf++){
      const int col = cb + cf*16 + cl;
      bc1v[cf] = bc1[col]; wc2v[cf] = wc2[col];
    }
#pragma unroll
    for (int fr = 0; fr < 4; fr++){
      float rs[4] = {0,0,0,0};
#pragma unroll
      for (int cf = 0; cf < 4; cf++)
#pragma unroll
        for (int j = 0; j < 4; j++)
          rs[j] += fmaxf(a2[fr][cf][j] + bc1v[cf], 0.f) * wc2v[cf];
#pragma unroll
      for (int j = 0; j < 4; j++){
        for (int m = 1; m < 16; m <<= 1) rs[j] += __shfl_xor(rs[j], m);
      }
      if (cl == 0){
#pragma unroll
        for (int j = 0; j < 4; j++) cpart[w][fr*16 + 4*g + j] = rs[j];
      }
    }
  }
  __syncthreads();
  if (tid < ET){
    const float cp = cpart[0][tid] + cpart[1][tid] + cpart[2][tid] + cpart[3][tid] + bc2[0];
    const float cc = tanhf(cp) * 0.1f;
    const int d = didx[tid];
    atomicAdd(&pos_delta[d*3+0], dir_s[tid][0]*cc);
    atomicAdd(&pos_delta[d*3+1], dir_s[tid][1]*cc);
    atomicAdd(&pos_delta[d*3+2], dir_s[tid][2]*cc);
  }
}

// ---------------- fusion gate/mix (one wave per node) ----------------
__global__ void fusion_mix(const float* __restrict__ gatez,
                           const float* __restrict__ gb2,
                           const float* __restrict__ s1p, const float* __restrict__ s2p,
                           const float* __restrict__ hef,
                           const float* __restrict__ pos,
                           float* hf32, short* __restrict__ hbf,
                           float* __restrict__ cur_pos, float* __restrict__ pos_delta,
                           float* __restrict__ agg)
{
  const int node = blockIdx.x * 4 + (threadIdx.x >> 6);
  const int l = threadIdx.x & 63;
  if (node >= NN) return;
  const float z = gatez[node] + gb2[0];
  const float gt = 1.f / (1.f + expf(-z));
  const float a = gt * s1p[0], b = (1.f - gt) * s2p[0];
#pragma unroll
  for (int k = 0; k < 4; k++){
    const int c = l + 64*k;
    const float hv = fmaxf(a*hf32[(size_t)node*256 + c] + b*hef[(size_t)node*256 + c], 0.f);
    hf32[(size_t)node*256 + c] = hv;
    hbf[(size_t)node*256 + c] = f2b(hv);
    agg[(size_t)node*256 + c] = 0.f;
  }
  if (l < 3){ cur_pos[node*3 + l] = pos[node*3 + l]; pos_delta[node*3 + l] = 0.f; }
}

// ---------------- final LN + head ----------------
__global__ void head_kernel(const float* __restrict__ hf32,
                            const float* __restrict__ fg, const float* __restrict__ fb,
                            const float* __restrict__ hw, const float* __restrict__ hbias,
                            float* __restrict__ out)
{
  const int node = blockIdx.x * 4 + (threadIdx.x >> 6);
  const int l = threadIdx.x & 63;
  if (node >= NN) return;
  float x[4], s = 0.f, q = 0.f;
#pragma unroll
  for (int k = 0; k < 4; k++){ x[k] = hf32[(size_t)node*256 + l + 64*k]; s += x[k]; q += x[k]*x[k]; }
#pragma unroll
  for (int m = 1; m < 64; m <<= 1){ s += __shfl_xor(s, m); q += __shfl_xor(q, m); }
  const float mu = s * (1.f/256.f);
  const float var = q * (1.f/256.f) - mu*mu;
  const float rs = rsqrtf(var + 1e-5f);
  float xn[4];
#pragma unroll
  for (int k = 0; k < 4; k++){ const int c = l + 64*k; xn[k] = (x[k]-mu)*rs*fg[c] + fb[c]; }
  for (int o = 0; o < 20; o++){
    float p = 0.f;
#pragma unroll
    for (int k = 0; k < 4; k++) p += xn[k] * hw[(l + 64*k)*20 + o];
#pragma unroll
    for (int m = 1; m < 64; m <<= 1) p += __shfl_xor(p, m);
    if (l == 0) out[node*20 + o] = p + hbias[o];
  }
}

extern "C" void kernel_launch(void* const* d_in, const int* in_sizes, int n_in,
                              void* d_out, int out_size, void* d_ws, size_t ws_size,
                              hipStream_t stream)
{
  (void)in_sizes; (void)n_in; (void)out_size; (void)ws_size;
  const float* x_struct = (const float*)d_in[0];
  const float* x_esm    = (const float*)d_in[1];
  const int*   eidx     = (const int*)d_in[2];
  const float* eattr    = (const float*)d_in[3];
  const float* pos      = (const float*)d_in[4];
  const float* struct_w = (const float*)d_in[5];
  const float* struct_b = (const float*)d_in[6];
  const float* esm_w    = (const float*)d_in[7];
  const float* esm_b    = (const float*)d_in[8];
  const float* gate_w1  = (const float*)d_in[9];
  const float* gate_b1  = (const float*)d_in[10];
  const float* gate_w2  = (const float*)d_in[11];
  const float* gate_b2  = (const float*)d_in[12];
  const float* s_scale  = (const float*)d_in[13];
  const float* e_scale  = (const float*)d_in[14];
  const float* edge_w1  = (const float*)d_in[15];
  const float* edge_b1  = (const float*)d_in[16];
  const float* edge_w2  = (const float*)d_in[17];
  const float* edge_b2  = (const float*)d_in[18];
  const float* coord_w1 = (const float*)d_in[19];
  const float* coord_b1 = (const float*)d_in[20];
  const float* coord_w2 = (const float*)d_in[21];
  const float* coord_b2 = (const float*)d_in[22];
  const float* node_w1  = (const float*)d_in[23];
  const float* node_b1  = (const float*)d_in[24];
  const float* ln_g     = (const float*)d_in[25];
  const float* ln_b     = (const float*)d_in[26];
  const float* fn_g     = (const float*)d_in[27];
  const float* fn_b     = (const float*)d_in[28];
  const float* head_w   = (const float*)d_in[29];
  const float* head_b   = (const float*)d_in[30];

  char* ws = (char*)d_ws;
  size_t off = 0;
  auto alloc = [&](size_t b){ size_t r = off; off += (b + 255) & ~(size_t)255; return r; };
  float* hf32 = (float*)(ws + alloc((size_t)NN*256*4));
  char* agghb = ws + alloc((size_t)NN*512*2);
  float* agg  = (float*)agghb;
  short* hb   = (short*)agghb;
  float* cpos = (float*)(ws + alloc((size_t)NN*3*4));
  float* pdel = (float*)(ws + alloc((size_t)NN*3*4));
  float* gatez= (float*)(ws + alloc((size_t)NN*4));
  short* hbf  = (short*)(ws + alloc((size_t)NN*256*2));
  char* AbufR = ws + alloc((size_t)NN*512*2);
  short* Abuf = (short*)AbufR;
  float* hef  = (float*)AbufR;
  int* hist   = (int*)(ws + alloc((size_t)NN*4));
  int* cursor = (int*)(ws + alloc((size_t)NN*4));
  int* ssrc   = (int*)(ws + alloc((size_t)EE*4));
  int* sdst   = (int*)(ws + alloc((size_t)EE*4));
  int* sperm  = (int*)(ws + alloc((size_t)EE*4));
  short* structT = (short*)(ws + alloc(256*64*2));
  short* esmT    = (short*)(ws + alloc(256*1280*2));
  short* gateT   = (short*)(ws + alloc(256*512*2));
  short* EW1T    = (short*)(ws + alloc((size_t)4*512*256*2));
  short* W2T     = (short*)(ws + alloc((size_t)4*256*256*2));
  short* Wc1T    = (short*)(ws + alloc((size_t)4*256*256*2));
  short* NW1T    = (short*)(ws + alloc((size_t)4*256*768*2));
  short* WeT     = (short*)(ws + alloc((size_t)4*256*32*2));

  // edge sort by dst (once per launch)
  zero_hist<<<dim3(40), 256, 0, stream>>>(hist);
  count_k<<<dim3(1250), 256, 0, stream>>>(eidx, hist);
  scan_k<<<dim3(1), 256, 0, stream>>>(hist, cursor);
  scatter_k<<<dim3(1250), 256, 0, stream>>>(eidx, cursor, ssrc, sdst, sperm);

  prep_fusion<<<dim3(1856), 256, 0, stream>>>(struct_w, esm_w, gate_w1, structT, esmT, gateT);
  prep_layer<<<dim3(1824, 4), 256, 0, stream>>>(edge_w1, edge_w2, coord_w1, node_w1,
                                                EW1T, W2T, Wc1T, NW1T, WeT);

  gemm_bf16<false,float,32><<<dim3(313,1), 256, 0, stream>>>(x_struct, 64, 64, structT, struct_b, NN,
                                                             hf32, 256, hb, 512);
  gemm_bf16<false,float,32><<<dim3(313,1), 256, 0, stream>>>(x_esm, 1280, 1280, esmT, esm_b, NN,
                                                             hef, 256, hb + 256, 512);
  gate_gemm<<<dim3(313), 256, 0, stream>>>(hb, gateT, gate_b1, gate_w2, gatez);
  fusion_mix<<<dim3(2500), 256, 0, stream>>>(gatez, gate_b2, s_scale, e_scale, hef, pos,
                                             hf32, hbf, cpos, pdel, agg);
  for (int i = 0; i < 4; i++){
    gemm_bf16<false,short,32><<<dim3(313,2), 256, 0, stream>>>(hbf, 256, 256,
                                                               EW1T + (size_t)i*512*256, nullptr, NN,
                                                               nullptr, 0, Abuf, 512);
    edge_kernel<<<dim3(EE/ET), 256, 0, stream>>>(ssrc, sdst, sperm, eattr, cpos, Abuf,
        WeT + (size_t)i*256*32, edge_b1 + (size_t)i*256,
        W2T + (size_t)i*256*256, edge_b2 + (size_t)i*256,
        Wc1T + (size_t)i*256*256, coord_b1 + (size_t)i*256,
        coord_w2 + (size_t)i*256, coord_b2 + i,
        agg, pdel);
    ln_gemm<<<dim3(313), 256, 0, stream>>>(hbf, agg, NW1T + (size_t)i*256*768,
                                           node_b1 + (size_t)i*256,
                                           ln_g + (size_t)i*256, ln_b + (size_t)i*256,
                                           hf32, agg, cpos, pdel);
  }
  head_kernel<<<dim3(2500), 256, 0, stream>>>(hf32, fn_g, fn_b, head_w, head_b, (float*)d_out);
}